// Round 11
// baseline (133.134 us; speedup 1.0000x reference)
//
#include <hip/hip_runtime.h>
#include <math.h>

#define T_TOK 16384   // 4*4096 tokens
#define NEXP  64
#define STR   68      // LDS row stride (floats): 4-aligned for b128, 68%32=4

// Workspace layout (floats):
//   ws[0..63]   : expert load sums
//   ws[64]      : sum of z^2
//   ws[66]      : block-done counter (int)
//
// d_out layout (floats, out_size = 65537):
//   [0, 32768)      top-2 renormalized scores [token][2]
//   [32768, 65536)  top-2 expert indices as floats [token][2]
//   [65536]         total_loss

__global__ void moe_zero(float* __restrict__ ws) {
    if (threadIdx.x < 128) ws[threadIdx.x] = 0.f;
}

// ---------------------------------------------------------------------------
// main: 8x8 register-tiled fp32 GEMM, k-major LDS. Block = 64 t x 64 e,
// 1024 threads = 16 waves, each wave = one 4-k slice per 64-k step (16-way
// k-split). Lane tile 8t x 8e: per k, 2 x-b128 + 2 w-b128 = 64 B feed 64
// FMAs (1 B/lane-MAC — half of round 9's 2 B/MAC; round 9 was LDS-return-BW
// bound). w staged straight from gate_w[e][k] (k-major rows) — no prep
// transpose. Staging writes use k = kc+16*i interleave -> 2-way banks (free).
// ---------------------------------------------------------------------------
#define FMA_ROW(i, xv) do {                                                    \
    acc[((i) << 3) + 0] = fmaf((xv), wf0.x, acc[((i) << 3) + 0]);              \
    acc[((i) << 3) + 1] = fmaf((xv), wf0.y, acc[((i) << 3) + 1]);              \
    acc[((i) << 3) + 2] = fmaf((xv), wf0.z, acc[((i) << 3) + 2]);              \
    acc[((i) << 3) + 3] = fmaf((xv), wf0.w, acc[((i) << 3) + 3]);              \
    acc[((i) << 3) + 4] = fmaf((xv), wf1.x, acc[((i) << 3) + 4]);              \
    acc[((i) << 3) + 5] = fmaf((xv), wf1.y, acc[((i) << 3) + 5]);              \
    acc[((i) << 3) + 6] = fmaf((xv), wf1.z, acc[((i) << 3) + 6]);              \
    acc[((i) << 3) + 7] = fmaf((xv), wf1.w, acc[((i) << 3) + 7]);              \
} while (0)

__launch_bounds__(1024, 4)
__global__ void moe_main(const float* __restrict__ x,
                         const float* __restrict__ gw,     // gate_w [64][1024]
                         float* __restrict__ acc_ws,
                         float* __restrict__ out) {
    __shared__ __align__(16) float xbuf[64 * STR];   // x slab [k][t], 17.4 KB
    __shared__ __align__(16) float wbuf[64 * STR];   // w slab [k][e]
    __shared__ __align__(16) float sc[64 * STR];     // logits [t][e]
    __shared__ float row_inv[64];
    __shared__ float colpart[16][64];
    __shared__ int   is_last;

    const int tid  = threadIdx.x;
    const int lane = tid & 63;
    const int wv   = tid >> 6;                                   // 0..15
    const int kbase = __builtin_amdgcn_readfirstlane(wv << 2);   // k-slice base
    const int tq = lane >> 3;            // token octet 0..7
    const int eq = lane & 7;             // expert octet 0..7
    const int tok0 = blockIdx.x << 6;

    // ---- staging: per thread 4 x-floats + 4 w-floats per 64-k step.
    // k = s*64 + kc + 16*i  (i=0..3): global reads are 64B-contiguous runs,
    // LDS writes land 2-way per bank (free).
    const int srow = tid >> 4;           // 0..63: token row for x, expert for w
    const int kc   = tid & 15;
    const float* gx = x  + ((size_t)(tok0 + srow) << 10) + kc;
    const float* gwp = gw + ((size_t)srow << 10) + kc;
    const int slo = kc * STR + srow;     // + i*16*STR for i-th float

    float acc[64];
#pragma unroll
    for (int i = 0; i < 64; ++i) acc[i] = 0.f;

    // prologue prefetch of step 0 (named scalars — nothing to spill)
    float px0 = gx[0],  px1 = gx[16],  px2 = gx[32],  px3 = gx[48];
    float pw0 = gwp[0], pw1 = gwp[16], pw2 = gwp[32], pw3 = gwp[48];

    const float* xr = xbuf + kbase * STR + (tq << 3);
    const float* wr = wbuf + kbase * STR + (eq << 3);

#pragma unroll 1
    for (int s = 0; s < 16; ++s) {
        __syncthreads();                                  // bufs free
        xbuf[slo]            = px0;
        xbuf[slo + 16 * STR] = px1;
        xbuf[slo + 32 * STR] = px2;
        xbuf[slo + 48 * STR] = px3;
        wbuf[slo]            = pw0;
        wbuf[slo + 16 * STR] = pw1;
        wbuf[slo + 32 * STR] = pw2;
        wbuf[slo + 48 * STR] = pw3;
        __syncthreads();                                  // bufs ready
        if (s < 15) {                                     // prefetch next step
            const float* g2 = gx  + ((s + 1) << 6);
            const float* g3 = gwp + ((s + 1) << 6);
            px0 = g2[0]; px1 = g2[16]; px2 = g2[32]; px3 = g2[48];
            pw0 = g3[0]; pw1 = g3[16]; pw2 = g3[32]; pw3 = g3[48];
        }
#pragma unroll
        for (int kk = 0; kk < 4; ++kk) {
            float4 xf0 = *(const float4*)(xr + kk * STR);
            float4 xf1 = *(const float4*)(xr + kk * STR + 4);
            float4 wf0 = *(const float4*)(wr + kk * STR);
            float4 wf1 = *(const float4*)(wr + kk * STR + 4);
            FMA_ROW(0, xf0.x); FMA_ROW(1, xf0.y);
            FMA_ROW(2, xf0.z); FMA_ROW(3, xf0.w);
            FMA_ROW(4, xf1.x); FMA_ROW(5, xf1.y);
            FMA_ROW(6, xf1.z); FMA_ROW(7, xf1.w);
        }
    }

    // ---- combine 16 k-slice partials: two parallel 8-stage chains
    // (waves 0-7 -> sc, waves 8-15 -> xbuf), then vectorized merge.
    __syncthreads();                     // all GEMM reads of xbuf done
#pragma unroll 1
    for (int c = 0; c < 8; ++c) {
        if (wv == c) {                   // chain A into sc
#pragma unroll
            for (int i = 0; i < 8; ++i) {
                float* p = sc + ((tq << 3) + i) * STR + (eq << 3);
                float4 a0 = make_float4(acc[(i << 3) + 0], acc[(i << 3) + 1],
                                        acc[(i << 3) + 2], acc[(i << 3) + 3]);
                float4 a1 = make_float4(acc[(i << 3) + 4], acc[(i << 3) + 5],
                                        acc[(i << 3) + 6], acc[(i << 3) + 7]);
                if (c == 0) {
                    *(float4*)p = a0; *(float4*)(p + 4) = a1;
                } else {
                    float4 o0 = *(float4*)p, o1 = *(float4*)(p + 4);
                    o0.x += a0.x; o0.y += a0.y; o0.z += a0.z; o0.w += a0.w;
                    o1.x += a1.x; o1.y += a1.y; o1.z += a1.z; o1.w += a1.w;
                    *(float4*)p = o0; *(float4*)(p + 4) = o1;
                }
            }
        } else if (wv == 8 + c) {        // chain B into xbuf (reuse)
#pragma unroll
            for (int i = 0; i < 8; ++i) {
                float* p = xbuf + ((tq << 3) + i) * STR + (eq << 3);
                float4 a0 = make_float4(acc[(i << 3) + 0], acc[(i << 3) + 1],
                                        acc[(i << 3) + 2], acc[(i << 3) + 3]);
                float4 a1 = make_float4(acc[(i << 3) + 4], acc[(i << 3) + 5],
                                        acc[(i << 3) + 6], acc[(i << 3) + 7]);
                if (c == 0) {
                    *(float4*)p = a0; *(float4*)(p + 4) = a1;
                } else {
                    float4 o0 = *(float4*)p, o1 = *(float4*)(p + 4);
                    o0.x += a0.x; o0.y += a0.y; o0.z += a0.z; o0.w += a0.w;
                    o1.x += a1.x; o1.y += a1.y; o1.z += a1.z; o1.w += a1.w;
                    *(float4*)p = o0; *(float4*)(p + 4) = o1;
                }
            }
        }
        __syncthreads();
    }
    {   // merge: sc += xbuf — GRID-STRIDE over all 1088 float4s (the round-10
        // bug: `tid < 1088` with 1024 threads left the last 64 float4s =
        // tokens ~60-63 unmerged -> wrong top-2 indices).
        float4* s4 = (float4*)sc;
        const float4* b4 = (const float4*)xbuf;
        for (int i = tid; i < (64 * STR) / 4; i += 1024) {
            float4 a = s4[i], b = b4[i];
            a.x += b.x; a.y += b.y; a.z += b.z; a.w += b.w;
            s4[i] = a;
        }
    }
    __syncthreads();

    // ---- per-token epilogue (serial, proven absmax 0)
    if (tid < 64) {
        const int r = tid;
        const float* srow2 = sc + r * STR;
        float v1 = -1e30f, v2 = -1e30f;
        int i1 = 0, i2 = 0;
        for (int j = 0; j < 64; ++j) {
            float l = srow2[j];
            if (l > v1)      { v2 = v1; i2 = i1; v1 = l; i1 = j; }
            else if (l > v2) { v2 = l; i2 = j; }
        }
        float m = v1;
        float ssum = 0.f;
        for (int j = 0; j < 64; ++j) {
            float ev = expf(srow2[j] - m);
            ssum += ev;
            sc[r * STR + j] = ev;
        }
        float inv = 1.f / ssum;
        row_inv[r] = inv;
        float z = m + logf(ssum);
        float zsq = z * z;
#pragma unroll
        for (int off = 32; off > 0; off >>= 1) zsq += __shfl_down(zsq, off);
        if (lane == 0) atomicAdd(acc_ws + 64, zsq);

        float p1s = inv;                        // exp(v1-m) == 1
        float p2s = expf(v2 - m) * inv;
        float bb  = expf(p2s - p1s);
        float s1 = 1.f / (1.f + bb);
        float s2 = bb * s1;
        int t = tok0 + r;
        out[2 * t]     = s1;
        out[2 * t + 1] = s2;
        out[2 * T_TOK + 2 * t]     = (float)i1;
        out[2 * T_TOK + 2 * t + 1] = (float)i2;
    }
    __syncthreads();

    // ---- expert load column sums (16 row-groups of 4 rows)
    {
        int e  = tid & 63;
        int rg = tid >> 6;                      // 0..15
        float sum = 0.f;
#pragma unroll
        for (int r2 = 0; r2 < 4; ++r2) {
            int row = (rg << 2) + r2;
            sum += sc[row * STR + e] * row_inv[row];
        }
        colpart[rg][e] = sum;
    }
    __syncthreads();
    if (tid < 64) {
        float tot = 0.f;
#pragma unroll
        for (int rg = 0; rg < 16; ++rg) tot += colpart[rg][tid];
        atomicAdd(acc_ws + tid, tot);           // device-scope
    }

    // ---- last-block finalize
    __syncthreads();
    if (tid == 0) {
        __threadfence();
        int old = __hip_atomic_fetch_add((int*)(acc_ws + 66), 1,
                                         __ATOMIC_ACQ_REL, __HIP_MEMORY_SCOPE_AGENT);
        is_last = (old == 255) ? 1 : 0;
    }
    __syncthreads();
    if (is_last && tid < 64) {
        __threadfence();
        float load = __hip_atomic_load(acc_ws + tid, __ATOMIC_RELAXED,
                                       __HIP_MEMORY_SCOPE_AGENT) * (1.f / 16384.f);
        float d = load - (1.f / 64.f);
        float v = d * d;
#pragma unroll
        for (int off = 32; off > 0; off >>= 1) v += __shfl_down(v, off);
        if (tid == 0) {
            float zsum = __hip_atomic_load(acc_ws + 64, __ATOMIC_RELAXED,
                                           __HIP_MEMORY_SCOPE_AGENT);
            float lb = 0.01f * 64.f * v;
            float zl = 1e-4f * zsum * (1.f / 16384.f);
            out[4 * T_TOK] = lb + zl;
        }
    }
}

extern "C" void kernel_launch(void* const* d_in, const int* in_sizes, int n_in,
                              void* d_out, int out_size, void* d_ws, size_t ws_size,
                              hipStream_t stream) {
    const float* x  = (const float*)d_in[0];   // [4,4096,1024] fp32
    const float* gw = (const float*)d_in[1];   // [64,1024] fp32
    float* out = (float*)d_out;                // 65537 fp32
    float* ws  = (float*)d_ws;

    moe_zero<<<1, 128, 0, stream>>>(ws);
    moe_main<<<256, 1024, 0, stream>>>(x, gw, ws, out);
}